// Round 1
// baseline (2267.580 us; speedup 1.0000x reference)
//
#include <hip/hip_runtime.h>
#include <cstdint>
#include <cstddef>

#define N1 4096
#define N2 16384
#define C1 256
#define C2 128
#define HH 256

// ---------------------------------------------------------------------------
// Kernel 1: three_nn + interpolation weights.
// Replicates the numpy fp32 arithmetic EXACTLY (expanded-form d2, no FMA
// contraction, same association order, stable strict-< top-3) so neighbor
// selection matches the reference bit-for-bit even at near-ties.
// Block = 64 threads (1 wave, 1 query/lane); all 4096 known points staged
// in LDS as float4(x,y,z,|k|^2); inner loop reads are wave-uniform
// (broadcast, conflict-free).
// ---------------------------------------------------------------------------
__global__ __launch_bounds__(64) void k_three_nn(
    const float* __restrict__ p1, const float* __restrict__ p2,
    float* __restrict__ wbuf, int* __restrict__ ibuf) {
  __shared__ float4 pts[N1];
  const int t = threadIdx.x;
  const int bx = blockIdx.x;
  const int b = bx >> 8;            // 256 n-tiles of 64 per batch
  const int n0 = (bx & 255) << 6;

  const float* p1b = p1 + (size_t)b * 3 * N1;
  for (int m = 0; m < N1 / 64; ++m) {
    int j = (m << 6) + t;
    float x = p1b[j], y = p1b[N1 + j], z = p1b[2 * N1 + j];
    float sk = __fadd_rn(__fadd_rn(__fmul_rn(x, x), __fmul_rn(y, y)),
                         __fmul_rn(z, z));
    pts[j] = make_float4(x, y, z, sk);
  }
  __syncthreads();

  const float* p2b = p2 + (size_t)b * 3 * N2;
  const int n = n0 + t;
  float ux = p2b[n], uy = p2b[N2 + n], uz = p2b[2 * N2 + n];
  float su = __fadd_rn(__fadd_rn(__fmul_rn(ux, ux), __fmul_rn(uy, uy)),
                       __fmul_rn(uz, uz));

  float da = 3.0e38f, db = 3.0e38f, dc = 3.0e38f;
  int ia = 0, ib = 0, ic = 0;
  for (int j = 0; j < N1; ++j) {
    float4 p = pts[j];
    float dot = __fadd_rn(__fadd_rn(__fmul_rn(ux, p.x), __fmul_rn(uy, p.y)),
                          __fmul_rn(uz, p.z));
    // (su + sk) - 2*dot : exactly the reference expression, each op RN
    float dd = __fsub_rn(__fadd_rn(su, p.w), __fmul_rn(2.0f, dot));
    if (dd < dc) {                      // strict <: earliest index wins ties
      dc = dd; ic = j;
      if (dc < db) {
        float tf = dc; dc = db; db = tf; int ti = ic; ic = ib; ib = ti;
        if (db < da) {
          tf = db; db = da; da = tf; ti = ib; ib = ia; ia = ti;
        }
      }
    }
  }

  // weights: dist2=max(d2,0); dist=dist2^2; dist=max(dist,1e-10); w=inv/sum
  float qa = fmaxf(da, 0.0f), qb = fmaxf(db, 0.0f), qc = fmaxf(dc, 0.0f);
  qa = fmaxf(__fmul_rn(qa, qa), 1e-10f);
  qb = fmaxf(__fmul_rn(qb, qb), 1e-10f);
  qc = fmaxf(__fmul_rn(qc, qc), 1e-10f);
  float va = __fdiv_rn(1.0f, qa);
  float vb = __fdiv_rn(1.0f, qb);
  float vc = __fdiv_rn(1.0f, qc);
  float s = __fadd_rn(__fadd_rn(va, vb), vc);
  int gi = b * N2 + n;
  wbuf[gi]               = __fdiv_rn(va, s);
  wbuf[2 * N2 + gi]      = __fdiv_rn(vb, s);
  wbuf[4 * N2 + gi]      = __fdiv_rn(vc, s);
  ibuf[gi]          = ia;
  ibuf[2 * N2 + gi] = ib;
  ibuf[4 * N2 + gi] = ic;
}

// ---------------------------------------------------------------------------
// Kernel 2: transpose features1 [B,C1,N1] -> f1T [B,N1,C1] so the 3-NN
// gather reads contiguous 1KB rows.
// ---------------------------------------------------------------------------
__global__ __launch_bounds__(256) void k_transpose(
    const float* __restrict__ f1, float* __restrict__ f1T) {
  __shared__ float tile[64][65];
  const int bx = blockIdx.x;            // B * 4(ct) * 64(nt) = 512
  const int b = bx >> 8;
  const int rest = bx & 255;
  const int ct = rest >> 6;             // c-tile 0..3
  const int ntb = (rest & 63) << 6;     // n-tile base
  const int t = threadIdx.x;
  const int ln = t & 63, g = t >> 6;

  const float* src = f1 + ((size_t)b * C1 + ct * 64) * N1 + ntb;
  for (int k = 0; k < 16; ++k) {
    int c = (k << 2) + g;
    tile[c][ln] = src[(size_t)c * N1 + ln];
  }
  __syncthreads();
  float* dst = f1T + ((size_t)b * N1 + ntb) * C1 + ct * 64;
  for (int k = 0; k < 16; ++k) {
    int nn = (k << 2) + g;
    dst[(size_t)nn * C1 + ln] = tile[ln][nn];
  }
}

// ---------------------------------------------------------------------------
// Kernel 3: fused interp-gather + concat + conv1+BN+ReLU + conv2+BN+ReLU.
// Block = 256 threads (4 waves), n-tile = 64 columns.
//   sX LDS [256][64] holds the interpolated C1 rows (64KB); the C2=128
//   features2 rows are streamed straight from global during GEMM1.
//   After GEMM1 the same LDS holds h [256][64] for GEMM2.
// Each wave owns a 64-row o-range; each lane owns one column; 64 fp32
// accumulators per lane, W rows read as float4 from wave-uniform addresses.
// ---------------------------------------------------------------------------
__global__ __launch_bounds__(256, 1) void k_fused(
    const float* __restrict__ f1T, const float* __restrict__ f2,
    const float* __restrict__ wbuf, const int* __restrict__ ibuf,
    const float* __restrict__ W1, const float* __restrict__ bb1,
    const float* __restrict__ g1, const float* __restrict__ be1,
    const float* __restrict__ mm1, const float* __restrict__ vv1,
    const float* __restrict__ W2, const float* __restrict__ bb2,
    const float* __restrict__ g2, const float* __restrict__ be2,
    const float* __restrict__ mm2, const float* __restrict__ vv2,
    float* __restrict__ out) {
  __shared__ float sX[C1 * 64];          // 64KB, reused as h after GEMM1
  const int t = threadIdx.x;
  const int bx = blockIdx.x;
  const int b = bx >> 8;                 // 256 n-tiles per batch
  const int n0 = (bx & 255) << 6;

  // ---- Phase A: gather + interpolate C1 rows into sX[c][n] ----
  {
    const int nn = t >> 2, q = t & 3;    // 4 threads per column, 64 c each
    const int gi = b * N2 + n0 + nn;
    const float w0 = wbuf[gi], w1 = wbuf[2 * N2 + gi], w2 = wbuf[4 * N2 + gi];
    const int i0 = ibuf[gi], i1 = ibuf[2 * N2 + gi], i2 = ibuf[4 * N2 + gi];
    const float4* r0 = (const float4*)(f1T + ((size_t)b * N1 + i0) * C1);
    const float4* r1 = (const float4*)(f1T + ((size_t)b * N1 + i1) * C1);
    const float4* r2 = (const float4*)(f1T + ((size_t)b * N1 + i2) * C1);
#pragma unroll 4
    for (int m = 0; m < 16; ++m) {
      int idx4 = (q << 4) + m;           // float4 index within the row
      float4 a = r0[idx4], c4 = r1[idx4], d4 = r2[idx4];
      int c = idx4 << 2;
      sX[(c + 0) * 64 + nn] = fmaf(w0, a.x, fmaf(w1, c4.x, w2 * d4.x));
      sX[(c + 1) * 64 + nn] = fmaf(w0, a.y, fmaf(w1, c4.y, w2 * d4.y));
      sX[(c + 2) * 64 + nn] = fmaf(w0, a.z, fmaf(w1, c4.z, w2 * d4.z));
      sX[(c + 3) * 64 + nn] = fmaf(w0, a.w, fmaf(w1, c4.w, w2 * d4.w));
    }
  }
  __syncthreads();

  const int lane = t & 63;
  const int wv = __builtin_amdgcn_readfirstlane(t >> 6);
  const int ob = wv << 6;                // this wave's 64-row o-range

  float acc[64];
#pragma unroll
  for (int o = 0; o < 64; ++o) acc[o] = 0.0f;

  // ---- GEMM1: K = 384 in chunks of 32 (8 LDS chunks + 4 global f2 chunks)
  for (int ch = 0; ch < 8; ++ch) {
    float Xc[32];
#pragma unroll
    for (int j = 0; j < 32; ++j) Xc[j] = sX[(ch * 32 + j) * 64 + lane];
#pragma unroll
    for (int o = 0; o < 64; o += 2) {
      const float4* Wr0 = (const float4*)(W1 + (size_t)(ob + o) * 384 + ch * 32);
      const float4* Wr1 = (const float4*)(W1 + (size_t)(ob + o + 1) * 384 + ch * 32);
      float a0 = acc[o], a1 = acc[o + 1];
#pragma unroll
      for (int qq = 0; qq < 8; ++qq) {
        float4 u0 = Wr0[qq], u1 = Wr1[qq];
        a0 = fmaf(u0.x, Xc[qq * 4 + 0], a0);
        a0 = fmaf(u0.y, Xc[qq * 4 + 1], a0);
        a0 = fmaf(u0.z, Xc[qq * 4 + 2], a0);
        a0 = fmaf(u0.w, Xc[qq * 4 + 3], a0);
        a1 = fmaf(u1.x, Xc[qq * 4 + 0], a1);
        a1 = fmaf(u1.y, Xc[qq * 4 + 1], a1);
        a1 = fmaf(u1.z, Xc[qq * 4 + 2], a1);
        a1 = fmaf(u1.w, Xc[qq * 4 + 3], a1);
      }
      acc[o] = a0; acc[o + 1] = a1;
    }
  }
  {
    const float* f2b = f2 + (size_t)b * C2 * N2 + n0 + lane;
    for (int ch = 8; ch < 12; ++ch) {
      float Xc[32];
#pragma unroll
      for (int j = 0; j < 32; ++j)
        Xc[j] = f2b[(size_t)(ch * 32 + j - 256) * N2];
#pragma unroll
      for (int o = 0; o < 64; o += 2) {
        const float4* Wr0 = (const float4*)(W1 + (size_t)(ob + o) * 384 + ch * 32);
        const float4* Wr1 = (const float4*)(W1 + (size_t)(ob + o + 1) * 384 + ch * 32);
        float a0 = acc[o], a1 = acc[o + 1];
#pragma unroll
        for (int qq = 0; qq < 8; ++qq) {
          float4 u0 = Wr0[qq], u1 = Wr1[qq];
          a0 = fmaf(u0.x, Xc[qq * 4 + 0], a0);
          a0 = fmaf(u0.y, Xc[qq * 4 + 1], a0);
          a0 = fmaf(u0.z, Xc[qq * 4 + 2], a0);
          a0 = fmaf(u0.w, Xc[qq * 4 + 3], a0);
          a1 = fmaf(u1.x, Xc[qq * 4 + 0], a1);
          a1 = fmaf(u1.y, Xc[qq * 4 + 1], a1);
          a1 = fmaf(u1.z, Xc[qq * 4 + 2], a1);
          a1 = fmaf(u1.w, Xc[qq * 4 + 3], a1);
        }
        acc[o] = a0; acc[o + 1] = a1;
      }
    }
  }
  __syncthreads();   // all waves done reading sX

  // ---- BN1 + ReLU -> h into LDS (alias sX) ----
#pragma unroll
  for (int o = 0; o < 64; ++o) {
    int oo = ob + o;
    float sc = g1[oo] / sqrtf(vv1[oo] + 1e-3f);
    float sh = fmaf(bb1[oo] - mm1[oo], sc, be1[oo]);
    float val = fmaf(acc[o], sc, sh);
    sX[oo * 64 + lane] = fmaxf(val, 0.0f);
  }
  __syncthreads();

  // ---- GEMM2: K = 256 in 8 LDS chunks ----
  float ac2[64];
#pragma unroll
  for (int o = 0; o < 64; ++o) ac2[o] = 0.0f;
  for (int ch = 0; ch < 8; ++ch) {
    float Xc[32];
#pragma unroll
    for (int j = 0; j < 32; ++j) Xc[j] = sX[(ch * 32 + j) * 64 + lane];
#pragma unroll
    for (int o = 0; o < 64; o += 2) {
      const float4* Wr0 = (const float4*)(W2 + (size_t)(ob + o) * 256 + ch * 32);
      const float4* Wr1 = (const float4*)(W2 + (size_t)(ob + o + 1) * 256 + ch * 32);
      float a0 = ac2[o], a1 = ac2[o + 1];
#pragma unroll
      for (int qq = 0; qq < 8; ++qq) {
        float4 u0 = Wr0[qq], u1 = Wr1[qq];
        a0 = fmaf(u0.x, Xc[qq * 4 + 0], a0);
        a0 = fmaf(u0.y, Xc[qq * 4 + 1], a0);
        a0 = fmaf(u0.z, Xc[qq * 4 + 2], a0);
        a0 = fmaf(u0.w, Xc[qq * 4 + 3], a0);
        a1 = fmaf(u1.x, Xc[qq * 4 + 0], a1);
        a1 = fmaf(u1.y, Xc[qq * 4 + 1], a1);
        a1 = fmaf(u1.z, Xc[qq * 4 + 2], a1);
        a1 = fmaf(u1.w, Xc[qq * 4 + 3], a1);
      }
      ac2[o] = a0; ac2[o + 1] = a1;
    }
  }

  // ---- BN2 + ReLU -> out ----
  float* outb = out + (size_t)b * HH * N2 + n0;
#pragma unroll
  for (int o = 0; o < 64; ++o) {
    int oo = ob + o;
    float sc = g2[oo] / sqrtf(vv2[oo] + 1e-3f);
    float sh = fmaf(bb2[oo] - mm2[oo], sc, be2[oo]);
    float val = fmaf(ac2[o], sc, sh);
    outb[(size_t)oo * N2 + lane] = fmaxf(val, 0.0f);
  }
}

// ---------------------------------------------------------------------------
extern "C" void kernel_launch(void* const* d_in, const int* in_sizes, int n_in,
                              void* d_out, int out_size, void* d_ws, size_t ws_size,
                              hipStream_t stream) {
  const float* p1  = (const float*)d_in[0];
  const float* p2  = (const float*)d_in[1];
  const float* f1  = (const float*)d_in[2];
  const float* f2  = (const float*)d_in[3];
  const float* W1  = (const float*)d_in[4];
  const float* bb1 = (const float*)d_in[5];
  const float* g1  = (const float*)d_in[6];
  const float* be1 = (const float*)d_in[7];
  const float* mm1 = (const float*)d_in[8];
  const float* vv1 = (const float*)d_in[9];
  const float* W2  = (const float*)d_in[10];
  const float* bb2 = (const float*)d_in[11];
  const float* g2  = (const float*)d_in[12];
  const float* be2 = (const float*)d_in[13];
  const float* mm2 = (const float*)d_in[14];
  const float* vv2 = (const float*)d_in[15];
  float* out = (float*)d_out;

  // ws layout: weights [3][B*N2] | indices [3][B*N2] | f1T [B][N1][C1]
  float* wbuf = (float*)d_ws;
  int*   ibuf = (int*)((char*)d_ws + 3 * 2 * N2 * sizeof(float));   // +384KB
  float* f1T  = (float*)((char*)d_ws + 6 * 2 * N2 * sizeof(float)); // +768KB

  k_three_nn<<<512, 64, 0, stream>>>(p1, p2, wbuf, ibuf);
  k_transpose<<<512, 256, 0, stream>>>(f1, f1T);
  k_fused<<<512, 256, 0, stream>>>(f1T, f2, wbuf, ibuf,
                                   W1, bb1, g1, be1, mm1, vv1,
                                   W2, bb2, g2, be2, mm2, vv2, out);
}

// Round 2
// 176.550 us; speedup vs baseline: 12.8438x; 12.8438x over previous
//
#include <hip/hip_runtime.h>
#include <cstdint>
#include <cstddef>

#define N1 4096
#define N2 16384
#define C1 256
#define C2 128
#define HH 256
#define K1 384
#define BQ 32768          // B*N2 total queries
#define KPAD 392          // LDS k-stride (bf16 elems): 16B-aligned, banks balanced

typedef float  f32x4  __attribute__((ext_vector_type(4)));
typedef __bf16 bf16x8 __attribute__((ext_vector_type(8)));
typedef __bf16 bf16x4 __attribute__((ext_vector_type(4)));

// ---------------------------------------------------------------------------
// k_prep: pack points1 -> float4(x,y,z,|k|^2) [exact RN ops], convert W1/W2 to
// bf16 (RNE), fold BN into per-row scale/shift.
// ---------------------------------------------------------------------------
__global__ __launch_bounds__(256) void k_prep(
    const float* __restrict__ p1,
    const float* __restrict__ W1, const float* __restrict__ W2,
    const float* __restrict__ b1, const float* __restrict__ g1,
    const float* __restrict__ be1, const float* __restrict__ mm1,
    const float* __restrict__ vv1,
    const float* __restrict__ b2, const float* __restrict__ g2,
    const float* __restrict__ be2, const float* __restrict__ mm2,
    const float* __restrict__ vv2,
    float4* __restrict__ pts4, __bf16* __restrict__ W1b,
    __bf16* __restrict__ W2b, float* __restrict__ scsh) {
  int idx = blockIdx.x * 256 + threadIdx.x;      // grid 384*256 = 98304
  if (idx < HH * K1) W1b[idx] = (__bf16)W1[idx];
  if (idx < HH * HH) W2b[idx] = (__bf16)W2[idx];
  if (idx < 2 * N1) {
    int b = idx >> 12, j = idx & (N1 - 1);
    const float* p = p1 + (size_t)b * 3 * N1;
    float x = p[j], y = p[N1 + j], z = p[2 * N1 + j];
    float sk = __fadd_rn(__fadd_rn(__fmul_rn(x, x), __fmul_rn(y, y)),
                         __fmul_rn(z, z));
    pts4[idx] = make_float4(x, y, z, sk);
  }
  if (idx < HH) {
    float sc = g1[idx] / sqrtf(vv1[idx] + 1e-3f);
    scsh[idx]          = sc;
    scsh[HH + idx]     = fmaf(b1[idx] - mm1[idx], sc, be1[idx]);
    float s2 = g2[idx] / sqrtf(vv2[idx] + 1e-3f);
    scsh[2 * HH + idx] = s2;
    scsh[3 * HH + idx] = fmaf(b2[idx] - mm2[idx], s2, be2[idx]);
  }
}

// ---------------------------------------------------------------------------
// k_nn: chunked 3-NN. 512 blocks = 128 query-tiles x 4 point-chunks of 1024.
// Point reads are wave-uniform (scalarizable); per-pair arithmetic is the
// EXACT RN sequence of the numpy reference (expanded-form d2); strict-<
// insertion keeps earliest index on ties (top_k semantics).
// ---------------------------------------------------------------------------
__global__ __launch_bounds__(256) void k_nn(
    const float* __restrict__ p2, const float4* __restrict__ pts4,
    float* __restrict__ pd, int* __restrict__ pi) {
  const int bx = blockIdx.x;
  const int ch = bx & 3;
  const int qt = bx >> 2;            // 0..127
  const int b  = qt >> 6;            // uniform per block
  const int n  = ((qt & 63) << 8) + threadIdx.x;

  const float* p2b = p2 + (size_t)b * 3 * N2;
  float ux = p2b[n], uy = p2b[N2 + n], uz = p2b[2 * N2 + n];
  float su = __fadd_rn(__fadd_rn(__fmul_rn(ux, ux), __fmul_rn(uy, uy)),
                       __fmul_rn(uz, uz));

  const float4* pp = pts4 + b * N1 + ch * 1024;
  float da = 3.0e38f, db = 3.0e38f, dc = 3.0e38f;
  int ia = 0, ib = 0, ic = 0;
#pragma unroll 4
  for (int j = 0; j < 1024; ++j) {
    float4 p = pp[j];
    float dot = __fadd_rn(__fadd_rn(__fmul_rn(ux, p.x), __fmul_rn(uy, p.y)),
                          __fmul_rn(uz, p.z));
    float dd = __fsub_rn(__fadd_rn(su, p.w), __fmul_rn(2.0f, dot));
    int jj = ch * 1024 + j;
    if (dd < dc) {
      dc = dd; ic = jj;
      if (dc < db) {
        float tf = dc; dc = db; db = tf; int ti = ic; ic = ib; ib = ti;
        if (db < da) {
          tf = db; db = da; da = tf; ti = ib; ib = ia; ia = ti;
        }
      }
    }
  }
  int q = b * N2 + n;
  int base = (q * 4 + ch) * 3;
  pd[base] = da; pd[base + 1] = db; pd[base + 2] = dc;
  pi[base] = ia; pi[base + 1] = ib; pi[base + 2] = ic;
}

// ---------------------------------------------------------------------------
// k_merge: combine 4 chunk-partial top-3s (in chunk==index order -> identical
// tie semantics to a full scan), then the exact reference weight arithmetic.
// ---------------------------------------------------------------------------
__global__ __launch_bounds__(256) void k_merge(
    const float* __restrict__ pd, const int* __restrict__ pi,
    float* __restrict__ wbuf, int* __restrict__ ibuf) {
  int q = blockIdx.x * 256 + threadIdx.x;    // 128 blocks
  float da = 3.0e38f, db = 3.0e38f, dc = 3.0e38f;
  int ia = 0, ib = 0, ic = 0;
#pragma unroll
  for (int ch = 0; ch < 4; ++ch) {
    int base = (q * 4 + ch) * 3;
#pragma unroll
    for (int k = 0; k < 3; ++k) {
      float dd = pd[base + k];
      int jj = pi[base + k];
      if (dd < dc) {
        dc = dd; ic = jj;
        if (dc < db) {
          float tf = dc; dc = db; db = tf; int ti = ic; ic = ib; ib = ti;
          if (db < da) {
            tf = db; db = da; da = tf; ti = ib; ib = ia; ia = ti;
          }
        }
      }
    }
  }
  float qa = fmaxf(da, 0.0f), qb = fmaxf(db, 0.0f), qc = fmaxf(dc, 0.0f);
  qa = fmaxf(__fmul_rn(qa, qa), 1e-10f);
  qb = fmaxf(__fmul_rn(qb, qb), 1e-10f);
  qc = fmaxf(__fmul_rn(qc, qc), 1e-10f);
  float va = __fdiv_rn(1.0f, qa);
  float vb = __fdiv_rn(1.0f, qb);
  float vc = __fdiv_rn(1.0f, qc);
  float s = __fadd_rn(__fadd_rn(va, vb), vc);
  wbuf[q]           = __fdiv_rn(va, s);
  wbuf[BQ + q]      = __fdiv_rn(vb, s);
  wbuf[2 * BQ + q]  = __fdiv_rn(vc, s);
  ibuf[q]          = ia;
  ibuf[BQ + q]     = ib;
  ibuf[2 * BQ + q] = ic;
}

// ---------------------------------------------------------------------------
// k_transpose: features1 [B,C1,N1] -> f1T [B,N1,C1] (contiguous gather rows).
// ---------------------------------------------------------------------------
__global__ __launch_bounds__(256) void k_transpose(
    const float* __restrict__ f1, float* __restrict__ f1T) {
  __shared__ float tile[64][65];
  const int bx = blockIdx.x;            // B * 4(ct) * 64(nt) = 512
  const int b = bx >> 8;
  const int rest = bx & 255;
  const int ct = rest >> 6;
  const int ntb = (rest & 63) << 6;
  const int t = threadIdx.x;
  const int ln = t & 63, g = t >> 6;

  const float* src = f1 + ((size_t)b * C1 + ct * 64) * N1 + ntb;
  for (int k = 0; k < 16; ++k) {
    int c = (k << 2) + g;
    tile[c][ln] = src[(size_t)c * N1 + ln];
  }
  __syncthreads();
  float* dst = f1T + ((size_t)b * N1 + ntb) * C1 + ct * 64;
  for (int k = 0; k < 16; ++k) {
    int nn = (k << 2) + g;
    dst[(size_t)nn * C1 + ln] = tile[ln][nn];
  }
}

// ---------------------------------------------------------------------------
// k_fused: gather+interp -> bf16 LDS [col][k] -> MFMA GEMM1 -> BN1+ReLU ->
// bf16 LDS h -> MFMA GEMM2 -> BN2+ReLU -> out (fp32).
// 256 threads = 4 waves; wave wv owns output rows [wv*64, wv*64+64), all 64
// cols of the block's n-tile: 4x4 tiles of mfma_f32_16x16x32_bf16.
// ---------------------------------------------------------------------------
__global__ __launch_bounds__(256) void k_fused(
    const float* __restrict__ f1T, const float* __restrict__ f2,
    const float* __restrict__ wbuf, const int* __restrict__ ibuf,
    const __bf16* __restrict__ W1b, const __bf16* __restrict__ W2b,
    const float* __restrict__ scsh, float* __restrict__ out) {
  __shared__ __bf16 sX[64 * KPAD];       // 49KB; x for GEMM1, then h for GEMM2
  const int t = threadIdx.x;
  const int bx = blockIdx.x;
  const int b = bx >> 8;
  const int n0 = (bx & 255) << 6;

  // ---- Phase A1: interp C1 channels (k = 0..255) ----
  {
    const int nn = t >> 2, qq = t & 3;   // 4 threads per column
    const int gi = b * N2 + n0 + nn;
    const float w0 = wbuf[gi], w1 = wbuf[BQ + gi], w2 = wbuf[2 * BQ + gi];
    const int i0 = ibuf[gi], i1 = ibuf[BQ + gi], i2 = ibuf[2 * BQ + gi];
    const float4* r0 = (const float4*)(f1T + ((size_t)b * N1 + i0) * C1);
    const float4* r1 = (const float4*)(f1T + ((size_t)b * N1 + i1) * C1);
    const float4* r2 = (const float4*)(f1T + ((size_t)b * N1 + i2) * C1);
#pragma unroll 4
    for (int m = 0; m < 16; ++m) {
      int idx4 = (qq << 4) + m;
      float4 a = r0[idx4], c4 = r1[idx4], d4 = r2[idx4];
      bf16x4 v;
      v[0] = (__bf16)fmaf(w0, a.x, fmaf(w1, c4.x, w2 * d4.x));
      v[1] = (__bf16)fmaf(w0, a.y, fmaf(w1, c4.y, w2 * d4.y));
      v[2] = (__bf16)fmaf(w0, a.z, fmaf(w1, c4.z, w2 * d4.z));
      v[3] = (__bf16)fmaf(w0, a.w, fmaf(w1, c4.w, w2 * d4.w));
      *(bf16x4*)&sX[nn * KPAD + (idx4 << 2)] = v;
    }
  }
  // ---- Phase A2: features2 channels (k = 256..383) ----
  {
    const int col = t & 63, g = t >> 6;
    const float* f2b = f2 + (size_t)b * C2 * N2 + n0 + col;
#pragma unroll 2
    for (int m = 0; m < 8; ++m) {
      int c4 = (g << 5) + (m << 2);
      bf16x4 v;
      v[0] = (__bf16)f2b[(size_t)(c4 + 0) * N2];
      v[1] = (__bf16)f2b[(size_t)(c4 + 1) * N2];
      v[2] = (__bf16)f2b[(size_t)(c4 + 2) * N2];
      v[3] = (__bf16)f2b[(size_t)(c4 + 3) * N2];
      *(bf16x4*)&sX[col * KPAD + 256 + c4] = v;
    }
  }
  __syncthreads();

  const int l  = t & 63;
  const int wv = __builtin_amdgcn_readfirstlane(t >> 6);
  const int ob = wv << 6;
  const int lm = l & 15, lg = l >> 4;

  f32x4 acc[4][4];
#pragma unroll
  for (int mt = 0; mt < 4; ++mt)
#pragma unroll
    for (int nt = 0; nt < 4; ++nt) acc[mt][nt] = (f32x4)0.0f;

  // ---- GEMM1: K = 384 (12 k-steps) ----
  for (int ks = 0; ks < 12; ++ks) {
    bf16x8 af[4], bfr[4];
#pragma unroll
    for (int mt = 0; mt < 4; ++mt)
      af[mt] = *(const bf16x8*)(W1b + (size_t)(ob + mt * 16 + lm) * K1 +
                                ks * 32 + lg * 8);
#pragma unroll
    for (int nt = 0; nt < 4; ++nt)
      bfr[nt] = *(const bf16x8*)&sX[(nt * 16 + lm) * KPAD + ks * 32 + lg * 8];
#pragma unroll
    for (int mt = 0; mt < 4; ++mt)
#pragma unroll
      for (int nt = 0; nt < 4; ++nt)
        acc[mt][nt] = __builtin_amdgcn_mfma_f32_16x16x32_bf16(
            af[mt], bfr[nt], acc[mt][nt], 0, 0, 0);
  }
  __syncthreads();

  // ---- BN1 + ReLU -> h (bf16) back into sX ----
#pragma unroll
  for (int mt = 0; mt < 4; ++mt) {
    int rb = ob + mt * 16 + lg * 4;     // h-channel base (GEMM1 output row)
    float4 sc4 = *(const float4*)(scsh + rb);
    float4 sh4 = *(const float4*)(scsh + HH + rb);
#pragma unroll
    for (int nt = 0; nt < 4; ++nt) {
      int colc = nt * 16 + lm;
      bf16x4 v;
      v[0] = (__bf16)fmaxf(fmaf(acc[mt][nt][0], sc4.x, sh4.x), 0.0f);
      v[1] = (__bf16)fmaxf(fmaf(acc[mt][nt][1], sc4.y, sh4.y), 0.0f);
      v[2] = (__bf16)fmaxf(fmaf(acc[mt][nt][2], sc4.z, sh4.z), 0.0f);
      v[3] = (__bf16)fmaxf(fmaf(acc[mt][nt][3], sc4.w, sh4.w), 0.0f);
      *(bf16x4*)&sX[colc * KPAD + rb] = v;
    }
  }
  __syncthreads();

  // ---- GEMM2: K = 256 (8 k-steps) ----
  f32x4 ac2[4][4];
#pragma unroll
  for (int mt = 0; mt < 4; ++mt)
#pragma unroll
    for (int nt = 0; nt < 4; ++nt) ac2[mt][nt] = (f32x4)0.0f;
  for (int ks = 0; ks < 8; ++ks) {
    bf16x8 af[4], bfr[4];
#pragma unroll
    for (int mt = 0; mt < 4; ++mt)
      af[mt] = *(const bf16x8*)(W2b + (size_t)(ob + mt * 16 + lm) * HH +
                                ks * 32 + lg * 8);
#pragma unroll
    for (int nt = 0; nt < 4; ++nt)
      bfr[nt] = *(const bf16x8*)&sX[(nt * 16 + lm) * KPAD + ks * 32 + lg * 8];
#pragma unroll
    for (int mt = 0; mt < 4; ++mt)
#pragma unroll
      for (int nt = 0; nt < 4; ++nt)
        ac2[mt][nt] = __builtin_amdgcn_mfma_f32_16x16x32_bf16(
            af[mt], bfr[nt], ac2[mt][nt], 0, 0, 0);
  }

  // ---- BN2 + ReLU -> out (fp32) ----
  float* outb = out + (size_t)b * HH * N2 + n0;
#pragma unroll
  for (int mt = 0; mt < 4; ++mt) {
    int rb = ob + mt * 16 + lg * 4;
    float4 sc4 = *(const float4*)(scsh + 2 * HH + rb);
    float4 sh4 = *(const float4*)(scsh + 3 * HH + rb);
#pragma unroll
    for (int nt = 0; nt < 4; ++nt) {
      int colc = nt * 16 + lm;
      outb[(size_t)(rb + 0) * N2 + colc] =
          fmaxf(fmaf(ac2[mt][nt][0], sc4.x, sh4.x), 0.0f);
      outb[(size_t)(rb + 1) * N2 + colc] =
          fmaxf(fmaf(ac2[mt][nt][1], sc4.y, sh4.y), 0.0f);
      outb[(size_t)(rb + 2) * N2 + colc] =
          fmaxf(fmaf(ac2[mt][nt][2], sc4.z, sh4.z), 0.0f);
      outb[(size_t)(rb + 3) * N2 + colc] =
          fmaxf(fmaf(ac2[mt][nt][3], sc4.w, sh4.w), 0.0f);
    }
  }
}

// ---------------------------------------------------------------------------
extern "C" void kernel_launch(void* const* d_in, const int* in_sizes, int n_in,
                              void* d_out, int out_size, void* d_ws, size_t ws_size,
                              hipStream_t stream) {
  const float* p1  = (const float*)d_in[0];
  const float* p2  = (const float*)d_in[1];
  const float* f1  = (const float*)d_in[2];
  const float* f2  = (const float*)d_in[3];
  const float* W1  = (const float*)d_in[4];
  const float* bb1 = (const float*)d_in[5];
  const float* g1  = (const float*)d_in[6];
  const float* be1 = (const float*)d_in[7];
  const float* mm1 = (const float*)d_in[8];
  const float* vv1 = (const float*)d_in[9];
  const float* W2  = (const float*)d_in[10];
  const float* bb2 = (const float*)d_in[11];
  const float* g2  = (const float*)d_in[12];
  const float* be2 = (const float*)d_in[13];
  const float* mm2 = (const float*)d_in[14];
  const float* vv2 = (const float*)d_in[15];
  float* out = (float*)d_out;

  char* ws = (char*)d_ws;
  float*  f1T  = (float*)(ws);                       // 8,388,608 B
  float*  wbuf = (float*)(ws + 8388608);             //   393,216 B
  int*    ibuf = (int*)  (ws + 8781824);             //   393,216 B
  float*  pd   = (float*)(ws + 9175040);             // 1,572,864 B
  int*    pi   = (int*)  (ws + 10747904);            // 1,572,864 B
  float4* pts4 = (float4*)(ws + 12320768);           //   131,072 B
  __bf16* W1b  = (__bf16*)(ws + 12451840);           //   196,608 B
  __bf16* W2b  = (__bf16*)(ws + 12648448);           //   131,072 B
  float*  scsh = (float*)(ws + 12779520);            //     4,096 B

  k_prep<<<384, 256, 0, stream>>>(p1, W1, W2,
                                  bb1, g1, be1, mm1, vv1,
                                  bb2, g2, be2, mm2, vv2,
                                  pts4, W1b, W2b, scsh);
  k_nn<<<512, 256, 0, stream>>>(p2, pts4, pd, pi);
  k_merge<<<128, 256, 0, stream>>>(pd, pi, wbuf, ibuf);
  k_transpose<<<512, 256, 0, stream>>>(f1, f1T);
  k_fused<<<512, 256, 0, stream>>>(f1T, f2, wbuf, ibuf, W1b, W2b, scsh, out);
}

// Round 3
// 129.435 us; speedup vs baseline: 17.5191x; 1.3640x over previous
//
#include <hip/hip_runtime.h>
#include <cstdint>
#include <cstddef>

#define N1 4096
#define N2 16384
#define C1 256
#define C2 128
#define HH 256
#define K1 384
#define BQ 32768          // B*N2 total queries
#define KPAD 392          // LDS k-stride (bf16 elems): 16B-aligned, banks balanced
#define NCH 8             // k_nn point chunks

typedef float  f32x4  __attribute__((ext_vector_type(4)));
typedef __bf16 bf16x8 __attribute__((ext_vector_type(8)));
typedef __bf16 bf16x4 __attribute__((ext_vector_type(4)));

// ---------------------------------------------------------------------------
// k_prep: pack points1 -> float4(x,y,z,|k|^2) [exact RN ops], convert W1/W2 to
// bf16 (RNE), fold BN into per-row scale/shift.
// ---------------------------------------------------------------------------
__global__ __launch_bounds__(256) void k_prep(
    const float* __restrict__ p1,
    const float* __restrict__ W1, const float* __restrict__ W2,
    const float* __restrict__ b1, const float* __restrict__ g1,
    const float* __restrict__ be1, const float* __restrict__ mm1,
    const float* __restrict__ vv1,
    const float* __restrict__ b2, const float* __restrict__ g2,
    const float* __restrict__ be2, const float* __restrict__ mm2,
    const float* __restrict__ vv2,
    float4* __restrict__ pts4, __bf16* __restrict__ W1b,
    __bf16* __restrict__ W2b, float* __restrict__ scsh) {
  int idx = blockIdx.x * 256 + threadIdx.x;      // grid 384*256 = 98304
  if (idx < HH * K1) W1b[idx] = (__bf16)W1[idx];
  if (idx < HH * HH) W2b[idx] = (__bf16)W2[idx];
  if (idx < 2 * N1) {
    int b = idx >> 12, j = idx & (N1 - 1);
    const float* p = p1 + (size_t)b * 3 * N1;
    float x = p[j], y = p[N1 + j], z = p[2 * N1 + j];
    float sk = __fadd_rn(__fadd_rn(__fmul_rn(x, x), __fmul_rn(y, y)),
                         __fmul_rn(z, z));
    pts4[idx] = make_float4(x, y, z, sk);
  }
  if (idx < HH) {
    float sc = g1[idx] / sqrtf(vv1[idx] + 1e-3f);
    scsh[idx]          = sc;
    scsh[HH + idx]     = fmaf(b1[idx] - mm1[idx], sc, be1[idx]);
    float s2 = g2[idx] / sqrtf(vv2[idx] + 1e-3f);
    scsh[2 * HH + idx] = s2;
    scsh[3 * HH + idx] = fmaf(b2[idx] - mm2[idx], s2, be2[idx]);
  }
}

// Select-based stable top-3 insert: strict-< at every level means a tying new
// element goes AFTER the incumbent (earliest index wins) — identical to a
// sequential strict-< scan, i.e. stable top_k.
#define INS(da, db, dc, ia, ib, ic, dd, jj)                                    \
  {                                                                            \
    bool ca = (dd) < (da), cb = (dd) < (db), cc = (dd) < (dc);                 \
    dc = cb ? (db) : (cc ? (dd) : (dc));                                       \
    ic = cb ? (ib) : (cc ? (jj) : (ic));                                       \
    db = ca ? (da) : (cb ? (dd) : (db));                                       \
    ib = ca ? (ia) : (cb ? (jj) : (ib));                                       \
    da = ca ? (dd) : (da);                                                     \
    ia = ca ? (jj) : (ia);                                                     \
  }

// Lexicographic (d, idx) insert — used when merge order is not index order.
#define LEXINS(da, db, dc, ia, ib, ic, dd, jj)                                 \
  {                                                                            \
    bool ca = ((dd) < (da)) || ((dd) == (da) && (jj) < (ia));                  \
    bool cb = ((dd) < (db)) || ((dd) == (db) && (jj) < (ib));                  \
    bool cc = ((dd) < (dc)) || ((dd) == (dc) && (jj) < (ic));                  \
    dc = cb ? (db) : (cc ? (dd) : (dc));                                       \
    ic = cb ? (ib) : (cc ? (jj) : (ic));                                       \
    db = ca ? (da) : (cb ? (dd) : (db));                                       \
    ib = ca ? (ia) : (cb ? (jj) : (ib));                                       \
    da = ca ? (dd) : (da);                                                     \
    ia = ca ? (jj) : (ia);                                                     \
  }

// ---------------------------------------------------------------------------
// k_nn: chunked 3-NN. 1024 blocks = 128 query-tiles x 8 point-chunks of 512.
// Two independent top-3 chains per thread (even/odd points) double the ILP on
// the loop-carried select chain; the final lexicographic merge reproduces
// stable top-k semantics exactly. Distance arithmetic is the exact RN
// sequence of the numpy reference.
// ---------------------------------------------------------------------------
__global__ __launch_bounds__(256) void k_nn(
    const float* __restrict__ p2, const float4* __restrict__ pts4,
    float* __restrict__ pd, int* __restrict__ pi) {
  const int bx = blockIdx.x;
  const int ch = bx & (NCH - 1);
  const int qt = bx >> 3;            // 0..127
  const int b  = qt >> 6;            // uniform per block
  const int n  = ((qt & 63) << 8) + threadIdx.x;

  const float* p2b = p2 + (size_t)b * 3 * N2;
  float ux = p2b[n], uy = p2b[N2 + n], uz = p2b[2 * N2 + n];
  float su = __fadd_rn(__fadd_rn(__fmul_rn(ux, ux), __fmul_rn(uy, uy)),
                       __fmul_rn(uz, uz));

  const float4* pp = pts4 + b * N1 + ch * 512;
  const int j0 = ch * 512;
  float daA = 3.0e38f, dbA = 3.0e38f, dcA = 3.0e38f;
  float daB = 3.0e38f, dbB = 3.0e38f, dcB = 3.0e38f;
  int iaA = 0, ibA = 0, icA = 0, iaB = 0, ibB = 0, icB = 0;
#pragma unroll 4
  for (int j = 0; j < 512; j += 2) {
    float4 pA = pp[j];
    float4 pB = pp[j + 1];
    float dotA = __fadd_rn(__fadd_rn(__fmul_rn(ux, pA.x), __fmul_rn(uy, pA.y)),
                           __fmul_rn(uz, pA.z));
    float ddA = __fsub_rn(__fadd_rn(su, pA.w), __fmul_rn(2.0f, dotA));
    float dotB = __fadd_rn(__fadd_rn(__fmul_rn(ux, pB.x), __fmul_rn(uy, pB.y)),
                           __fmul_rn(uz, pB.z));
    float ddB = __fsub_rn(__fadd_rn(su, pB.w), __fmul_rn(2.0f, dotB));
    INS(daA, dbA, dcA, iaA, ibA, icA, ddA, j0 + j);
    INS(daB, dbB, dcB, iaB, ibB, icB, ddB, j0 + j + 1);
  }
  // merge chain B into chain A with (d, idx) lexicographic order
  LEXINS(daA, dbA, dcA, iaA, ibA, icA, daB, iaB);
  LEXINS(daA, dbA, dcA, iaA, ibA, icA, dbB, ibB);
  LEXINS(daA, dbA, dcA, iaA, ibA, icA, dcB, icB);

  int q = b * N2 + n;
  int base = (q * NCH + ch) * 3;
  pd[base] = daA; pd[base + 1] = dbA; pd[base + 2] = dcA;
  pi[base] = iaA; pi[base + 1] = ibA; pi[base + 2] = icA;
}

// ---------------------------------------------------------------------------
// k_merge: combine NCH chunk-partial top-3s (chunk order == index order and
// each partial is (d,idx)-sorted, so plain strict-< insertion reproduces
// stable top-k), then the exact reference weight arithmetic.
// ---------------------------------------------------------------------------
__global__ __launch_bounds__(256) void k_merge(
    const float* __restrict__ pd, const int* __restrict__ pi,
    float* __restrict__ wbuf, int* __restrict__ ibuf) {
  int q = blockIdx.x * 256 + threadIdx.x;    // 128 blocks
  float da = 3.0e38f, db = 3.0e38f, dc = 3.0e38f;
  int ia = 0, ib = 0, ic = 0;
#pragma unroll
  for (int ch = 0; ch < NCH; ++ch) {
    int base = (q * NCH + ch) * 3;
#pragma unroll
    for (int k = 0; k < 3; ++k) {
      float dd = pd[base + k];
      int jj = pi[base + k];
      INS(da, db, dc, ia, ib, ic, dd, jj);
    }
  }
  float qa = fmaxf(da, 0.0f), qb = fmaxf(db, 0.0f), qc = fmaxf(dc, 0.0f);
  qa = fmaxf(__fmul_rn(qa, qa), 1e-10f);
  qb = fmaxf(__fmul_rn(qb, qb), 1e-10f);
  qc = fmaxf(__fmul_rn(qc, qc), 1e-10f);
  float va = __fdiv_rn(1.0f, qa);
  float vb = __fdiv_rn(1.0f, qb);
  float vc = __fdiv_rn(1.0f, qc);
  float s = __fadd_rn(__fadd_rn(va, vb), vc);
  wbuf[q]           = __fdiv_rn(va, s);
  wbuf[BQ + q]      = __fdiv_rn(vb, s);
  wbuf[2 * BQ + q]  = __fdiv_rn(vc, s);
  ibuf[q]          = ia;
  ibuf[BQ + q]     = ib;
  ibuf[2 * BQ + q] = ic;
}

// ---------------------------------------------------------------------------
// k_transpose: features1 [B,C1,N1] -> f1T [B,N1,C1] (contiguous gather rows).
// NOTE: f1T aliases pd/pi — must launch after k_merge.
// ---------------------------------------------------------------------------
__global__ __launch_bounds__(256) void k_transpose(
    const float* __restrict__ f1, float* __restrict__ f1T) {
  __shared__ float tile[64][65];
  const int bx = blockIdx.x;            // B * 4(ct) * 64(nt) = 512
  const int b = bx >> 8;
  const int rest = bx & 255;
  const int ct = rest >> 6;
  const int ntb = (rest & 63) << 6;
  const int t = threadIdx.x;
  const int ln = t & 63, g = t >> 6;

  const float* src = f1 + ((size_t)b * C1 + ct * 64) * N1 + ntb;
  for (int k = 0; k < 16; ++k) {
    int c = (k << 2) + g;
    tile[c][ln] = src[(size_t)c * N1 + ln];
  }
  __syncthreads();
  float* dst = f1T + ((size_t)b * N1 + ntb) * C1 + ct * 64;
  for (int k = 0; k < 16; ++k) {
    int nn = (k << 2) + g;
    dst[(size_t)nn * C1 + ln] = tile[ln][nn];
  }
}

// ---------------------------------------------------------------------------
// k_fused: gather+interp -> bf16 LDS [col][k] -> MFMA GEMM1 -> BN1+ReLU ->
// bf16 LDS h -> MFMA GEMM2 -> BN2+ReLU -> out (fp32).
// 256 threads = 4 waves; wave wv owns output rows [wv*64, wv*64+64), all 64
// cols of the block's n-tile: 4x4 tiles of mfma_f32_16x16x32_bf16.
// ---------------------------------------------------------------------------
__global__ __launch_bounds__(256) void k_fused(
    const float* __restrict__ f1T, const float* __restrict__ f2,
    const float* __restrict__ wbuf, const int* __restrict__ ibuf,
    const __bf16* __restrict__ W1b, const __bf16* __restrict__ W2b,
    const float* __restrict__ scsh, float* __restrict__ out) {
  __shared__ __bf16 sX[64 * KPAD];       // 49KB; x for GEMM1, then h for GEMM2
  const int t = threadIdx.x;
  const int bx = blockIdx.x;
  const int b = bx >> 8;
  const int n0 = (bx & 255) << 6;

  // ---- Phase A1: interp C1 channels (k = 0..255) ----
  {
    const int nn = t >> 2, qq = t & 3;   // 4 threads per column
    const int gi = b * N2 + n0 + nn;
    const float w0 = wbuf[gi], w1 = wbuf[BQ + gi], w2 = wbuf[2 * BQ + gi];
    const int i0 = ibuf[gi], i1 = ibuf[BQ + gi], i2 = ibuf[2 * BQ + gi];
    const float4* r0 = (const float4*)(f1T + ((size_t)b * N1 + i0) * C1);
    const float4* r1 = (const float4*)(f1T + ((size_t)b * N1 + i1) * C1);
    const float4* r2 = (const float4*)(f1T + ((size_t)b * N1 + i2) * C1);
#pragma unroll 4
    for (int m = 0; m < 16; ++m) {
      int idx4 = (qq << 4) + m;
      float4 a = r0[idx4], c4 = r1[idx4], d4 = r2[idx4];
      bf16x4 v;
      v[0] = (__bf16)fmaf(w0, a.x, fmaf(w1, c4.x, w2 * d4.x));
      v[1] = (__bf16)fmaf(w0, a.y, fmaf(w1, c4.y, w2 * d4.y));
      v[2] = (__bf16)fmaf(w0, a.z, fmaf(w1, c4.z, w2 * d4.z));
      v[3] = (__bf16)fmaf(w0, a.w, fmaf(w1, c4.w, w2 * d4.w));
      *(bf16x4*)&sX[nn * KPAD + (idx4 << 2)] = v;
    }
  }
  // ---- Phase A2: features2 channels (k = 256..383) ----
  {
    const int col = t & 63, g = t >> 6;
    const float* f2b = f2 + (size_t)b * C2 * N2 + n0 + col;
#pragma unroll 2
    for (int m = 0; m < 8; ++m) {
      int c4 = (g << 5) + (m << 2);
      bf16x4 v;
      v[0] = (__bf16)f2b[(size_t)(c4 + 0) * N2];
      v[1] = (__bf16)f2b[(size_t)(c4 + 1) * N2];
      v[2] = (__bf16)f2b[(size_t)(c4 + 2) * N2];
      v[3] = (__bf16)f2b[(size_t)(c4 + 3) * N2];
      *(bf16x4*)&sX[col * KPAD + 256 + c4] = v;
    }
  }
  __syncthreads();

  const int l  = t & 63;
  const int wv = __builtin_amdgcn_readfirstlane(t >> 6);
  const int ob = wv << 6;
  const int lm = l & 15, lg = l >> 4;

  f32x4 acc[4][4];
#pragma unroll
  for (int mt = 0; mt < 4; ++mt)
#pragma unroll
    for (int nt = 0; nt < 4; ++nt) acc[mt][nt] = (f32x4)0.0f;

  // ---- GEMM1: K = 384 (12 k-steps) ----
  for (int ks = 0; ks < 12; ++ks) {
    bf16x8 af[4], bfr[4];
#pragma unroll
    for (int mt = 0; mt < 4; ++mt)
      af[mt] = *(const bf16x8*)(W1b + (size_t)(ob + mt * 16 + lm) * K1 +
                                ks * 32 + lg * 8);
#pragma unroll
    for (int nt = 0; nt < 4; ++nt)
      bfr[nt] = *(const bf16x8*)&sX[(nt * 16 + lm) * KPAD + ks * 32 + lg * 8];
#pragma unroll
    for (int mt = 0; mt < 4; ++mt)
#pragma unroll
      for (int nt = 0; nt < 4; ++nt)
        acc[mt][nt] = __builtin_amdgcn_mfma_f32_16x16x32_bf16(
            af[mt], bfr[nt], acc[mt][nt], 0, 0, 0);
  }
  __syncthreads();

  // ---- BN1 + ReLU -> h (bf16) back into sX ----
#pragma unroll
  for (int mt = 0; mt < 4; ++mt) {
    int rb = ob + mt * 16 + lg * 4;     // h-channel base (GEMM1 output row)
    float4 sc4 = *(const float4*)(scsh + rb);
    float4 sh4 = *(const float4*)(scsh + HH + rb);
#pragma unroll
    for (int nt = 0; nt < 4; ++nt) {
      int colc = nt * 16 + lm;
      bf16x4 v;
      v[0] = (__bf16)fmaxf(fmaf(acc[mt][nt][0], sc4.x, sh4.x), 0.0f);
      v[1] = (__bf16)fmaxf(fmaf(acc[mt][nt][1], sc4.y, sh4.y), 0.0f);
      v[2] = (__bf16)fmaxf(fmaf(acc[mt][nt][2], sc4.z, sh4.z), 0.0f);
      v[3] = (__bf16)fmaxf(fmaf(acc[mt][nt][3], sc4.w, sh4.w), 0.0f);
      *(bf16x4*)&sX[colc * KPAD + rb] = v;
    }
  }
  __syncthreads();

  // ---- GEMM2: K = 256 (8 k-steps) ----
  f32x4 ac2[4][4];
#pragma unroll
  for (int mt = 0; mt < 4; ++mt)
#pragma unroll
    for (int nt = 0; nt < 4; ++nt) ac2[mt][nt] = (f32x4)0.0f;
  for (int ks = 0; ks < 8; ++ks) {
    bf16x8 af[4], bfr[4];
#pragma unroll
    for (int mt = 0; mt < 4; ++mt)
      af[mt] = *(const bf16x8*)(W2b + (size_t)(ob + mt * 16 + lm) * HH +
                                ks * 32 + lg * 8);
#pragma unroll
    for (int nt = 0; nt < 4; ++nt)
      bfr[nt] = *(const bf16x8*)&sX[(nt * 16 + lm) * KPAD + ks * 32 + lg * 8];
#pragma unroll
    for (int mt = 0; mt < 4; ++mt)
#pragma unroll
      for (int nt = 0; nt < 4; ++nt)
        ac2[mt][nt] = __builtin_amdgcn_mfma_f32_16x16x32_bf16(
            af[mt], bfr[nt], ac2[mt][nt], 0, 0, 0);
  }

  // ---- BN2 + ReLU -> out (fp32) ----
  float* outb = out + (size_t)b * HH * N2 + n0;
#pragma unroll
  for (int mt = 0; mt < 4; ++mt) {
    int rb = ob + mt * 16 + lg * 4;
    float4 sc4 = *(const float4*)(scsh + 2 * HH + rb);
    float4 sh4 = *(const float4*)(scsh + 3 * HH + rb);
#pragma unroll
    for (int nt = 0; nt < 4; ++nt) {
      int colc = nt * 16 + lm;
      outb[(size_t)(rb + 0) * N2 + colc] =
          fmaxf(fmaf(ac2[mt][nt][0], sc4.x, sh4.x), 0.0f);
      outb[(size_t)(rb + 1) * N2 + colc] =
          fmaxf(fmaf(ac2[mt][nt][1], sc4.y, sh4.y), 0.0f);
      outb[(size_t)(rb + 2) * N2 + colc] =
          fmaxf(fmaf(ac2[mt][nt][2], sc4.z, sh4.z), 0.0f);
      outb[(size_t)(rb + 3) * N2 + colc] =
          fmaxf(fmaf(ac2[mt][nt][3], sc4.w, sh4.w), 0.0f);
    }
  }
}

// ---------------------------------------------------------------------------
extern "C" void kernel_launch(void* const* d_in, const int* in_sizes, int n_in,
                              void* d_out, int out_size, void* d_ws, size_t ws_size,
                              hipStream_t stream) {
  const float* p1  = (const float*)d_in[0];
  const float* p2  = (const float*)d_in[1];
  const float* f1  = (const float*)d_in[2];
  const float* f2  = (const float*)d_in[3];
  const float* W1  = (const float*)d_in[4];
  const float* bb1 = (const float*)d_in[5];
  const float* g1  = (const float*)d_in[6];
  const float* be1 = (const float*)d_in[7];
  const float* mm1 = (const float*)d_in[8];
  const float* vv1 = (const float*)d_in[9];
  const float* W2  = (const float*)d_in[10];
  const float* bb2 = (const float*)d_in[11];
  const float* g2  = (const float*)d_in[12];
  const float* be2 = (const float*)d_in[13];
  const float* mm2 = (const float*)d_in[14];
  const float* vv2 = (const float*)d_in[15];
  float* out = (float*)d_out;

  // ws layout. pd/pi live only between k_nn and k_merge, then the same bytes
  // are reused for f1T (k_transpose launches after k_merge).
  char* ws = (char*)d_ws;
  float*  pd   = (float*)(ws);                       // 3,145,728 B
  int*    pi   = (int*)  (ws + 3145728);             // 3,145,728 B
  float*  f1T  = (float*)(ws);                       // 8,388,608 B (alias)
  float*  wbuf = (float*)(ws + 8388608);             //   393,216 B
  int*    ibuf = (int*)  (ws + 8781824);             //   393,216 B
  float4* pts4 = (float4*)(ws + 9175040);            //   131,072 B
  __bf16* W1b  = (__bf16*)(ws + 9306112);            //   196,608 B
  __bf16* W2b  = (__bf16*)(ws + 9502720);            //   131,072 B
  float*  scsh = (float*)(ws + 9633792);             //     4,096 B

  k_prep<<<384, 256, 0, stream>>>(p1, W1, W2,
                                  bb1, g1, be1, mm1, vv1,
                                  bb2, g2, be2, mm2, vv2,
                                  pts4, W1b, W2b, scsh);
  k_nn<<<1024, 256, 0, stream>>>(p2, pts4, pd, pi);
  k_merge<<<128, 256, 0, stream>>>(pd, pi, wbuf, ibuf);
  k_transpose<<<512, 256, 0, stream>>>(f1, f1T);   // after k_merge: reuses pd/pi
  k_fused<<<512, 256, 0, stream>>>(f1T, f2, wbuf, ibuf, W1b, W2b, scsh, out);
}

// Round 4
// 126.225 us; speedup vs baseline: 17.9645x; 1.0254x over previous
//
#include <hip/hip_runtime.h>
#include <cstdint>
#include <cstddef>

#define N1 4096
#define N2 16384
#define C1 256
#define C2 128
#define HH 256
#define K1 384
#define BQ 32768          // B*N2 total queries
#define KPAD 392          // LDS k-stride (bf16 elems): 16B-aligned, banks balanced
#define NCH 16            // k_nn point chunks (256 points each)

typedef float  f32x4  __attribute__((ext_vector_type(4)));
typedef float  f32x2  __attribute__((ext_vector_type(2)));
typedef __bf16 bf16x8 __attribute__((ext_vector_type(8)));
typedef __bf16 bf16x4 __attribute__((ext_vector_type(4)));

// ---------------------------------------------------------------------------
// k_prep: pack points1 into pair-SoA [x0 x1 y0 y1 z0 z1 w0 w1] per 2 points
// (enables v_pk_*_f32 in k_nn), exact RN |k|^2; convert W1/W2 to bf16; fold
// BN into per-row scale/shift.
// ---------------------------------------------------------------------------
__global__ __launch_bounds__(256) void k_prep(
    const float* __restrict__ p1,
    const float* __restrict__ W1, const float* __restrict__ W2,
    const float* __restrict__ b1, const float* __restrict__ g1,
    const float* __restrict__ be1, const float* __restrict__ mm1,
    const float* __restrict__ vv1,
    const float* __restrict__ b2, const float* __restrict__ g2,
    const float* __restrict__ be2, const float* __restrict__ mm2,
    const float* __restrict__ vv2,
    float* __restrict__ pts8, __bf16* __restrict__ W1b,
    __bf16* __restrict__ W2b, float* __restrict__ scsh) {
  int idx = blockIdx.x * 256 + threadIdx.x;      // grid 384*256 = 98304
  if (idx < HH * K1) W1b[idx] = (__bf16)W1[idx];
  if (idx < HH * HH) W2b[idx] = (__bf16)W2[idx];
  if (idx < 2 * N1) {
    int b = idx >> 12, j = idx & (N1 - 1);
    const float* p = p1 + (size_t)b * 3 * N1;
    float x = p[j], y = p[N1 + j], z = p[2 * N1 + j];
    float sk = __fadd_rn(__fadd_rn(__fmul_rn(x, x), __fmul_rn(y, y)),
                         __fmul_rn(z, z));
    size_t base = ((size_t)b * (N1 / 2) + (j >> 1)) * 8 + (j & 1);
    pts8[base + 0] = x;
    pts8[base + 2] = y;
    pts8[base + 4] = z;
    pts8[base + 6] = sk;
  }
  if (idx < HH) {
    float sc = g1[idx] / sqrtf(vv1[idx] + 1e-3f);
    scsh[idx]          = sc;
    scsh[HH + idx]     = fmaf(b1[idx] - mm1[idx], sc, be1[idx]);
    float s2 = g2[idx] / sqrtf(vv2[idx] + 1e-3f);
    scsh[2 * HH + idx] = s2;
    scsh[3 * HH + idx] = fmaf(b2[idx] - mm2[idx], s2, be2[idx]);
  }
}

// Select-based stable top-3 insert (strict <: earliest index wins ties).
#define INS(da, db, dc, ia, ib, ic, dd, jj)                                    \
  {                                                                            \
    bool ca = (dd) < (da), cb = (dd) < (db), cc = (dd) < (dc);                 \
    dc = cb ? (db) : (cc ? (dd) : (dc));                                       \
    ic = cb ? (ib) : (cc ? (jj) : (ic));                                       \
    db = ca ? (da) : (cb ? (dd) : (db));                                       \
    ib = ca ? (ia) : (cb ? (jj) : (ib));                                       \
    da = ca ? (dd) : (da);                                                     \
    ia = ca ? (jj) : (ia);                                                     \
  }

// Hot-loop insert: values via min/med3 (3 ops, == sorted insert), indices via
// strict-< masks (stable, earliest index wins ties).
#define INS3(da, db, dc, ia, ib, ic, dd, jj)                                   \
  {                                                                            \
    bool ca = (dd) < (da), cb = (dd) < (db), cc = (dd) < (dc);                 \
    float ndb = __builtin_amdgcn_fmed3f((da), (dd), (db));                     \
    float ndc = __builtin_amdgcn_fmed3f((db), (dd), (dc));                     \
    float nda = fminf((da), (dd));                                             \
    int nic = cb ? (ib) : (cc ? (jj) : (ic));                                  \
    int nib = ca ? (ia) : (cb ? (jj) : (ib));                                  \
    int nia = ca ? (jj) : (ia);                                                \
    da = nda; db = ndb; dc = ndc; ia = nia; ib = nib; ic = nic;                \
  }

// Lexicographic (d, idx) insert — for merging chains whose order isn't index
// order.
#define LEXINS(da, db, dc, ia, ib, ic, dd, jj)                                 \
  {                                                                            \
    bool ca = ((dd) < (da)) || ((dd) == (da) && (jj) < (ia));                  \
    bool cb = ((dd) < (db)) || ((dd) == (db) && (jj) < (ib));                  \
    bool cc = ((dd) < (dc)) || ((dd) == (dc) && (jj) < (ic));                  \
    dc = cb ? (db) : (cc ? (dd) : (dc));                                       \
    ic = cb ? (ib) : (cc ? (jj) : (ic));                                       \
    db = ca ? (da) : (cb ? (dd) : (db));                                       \
    ib = ca ? (ia) : (cb ? (jj) : (ib));                                       \
    da = ca ? (dd) : (da);                                                     \
    ia = ca ? (jj) : (ia);                                                     \
  }

// ---------------------------------------------------------------------------
// k_nn: chunked 3-NN. 2048 blocks = 128 query-tiles x 16 point-chunks of 256.
// Packed-f32 distance math (2 points/instr), two independent top-3 chains
// (even/odd points), lexicographic end-merge => stable top-k semantics,
// arithmetic bit-identical to the numpy reference (contract(off) blocks FMA
// contraction; pk ops are per-lane RN).
// ---------------------------------------------------------------------------
__global__ __launch_bounds__(256) void k_nn(
    const float* __restrict__ p2, const float4* __restrict__ pts8,
    float* __restrict__ pd, unsigned short* __restrict__ pi) {
#pragma clang fp contract(off)
  const int bx = blockIdx.x;
  const int ch = bx & (NCH - 1);
  const int qt = bx >> 4;            // 0..127
  const int b  = qt >> 6;            // uniform per block
  const int n  = ((qt & 63) << 8) + threadIdx.x;

  const float* p2b = p2 + (size_t)b * 3 * N2;
  float ux = p2b[n], uy = p2b[N2 + n], uz = p2b[2 * N2 + n];
  float su = __fadd_rn(__fadd_rn(__fmul_rn(ux, ux), __fmul_rn(uy, uy)),
                       __fmul_rn(uz, uz));
  f32x2 uxv = {ux, ux}, uyv = {uy, uy}, uzv = {uz, uz}, suv = {su, su};
  const f32x2 two = {2.0f, 2.0f};

  // pair-SoA: 2 float4 per point-pair
  const float4* pp = pts8 + ((size_t)b * (N1 / 2) + ch * 128) * 2;
  const int j0 = ch * 256;
  float daA = 3.0e38f, dbA = 3.0e38f, dcA = 3.0e38f;
  float daB = 3.0e38f, dbB = 3.0e38f, dcB = 3.0e38f;
  int iaA = 0, ibA = 0, icA = 0, iaB = 0, ibB = 0, icB = 0;
#pragma unroll 4
  for (int k = 0; k < 128; ++k) {
    float4 q0 = pp[2 * k];           // x0 x1 y0 y1
    float4 q1 = pp[2 * k + 1];       // z0 z1 w0 w1
    f32x2 X = {q0.x, q0.y}, Y = {q0.z, q0.w};
    f32x2 Z = {q1.x, q1.y}, Wp = {q1.z, q1.w};
    f32x2 t1 = uxv * X;
    f32x2 t2 = uyv * Y;
    f32x2 t3 = uzv * Z;
    f32x2 dot = (t1 + t2) + t3;
    f32x2 dd2 = (suv + Wp) - two * dot;
    INS3(daA, dbA, dcA, iaA, ibA, icA, dd2[0], j0 + 2 * k);
    INS3(daB, dbB, dcB, iaB, ibB, icB, dd2[1], j0 + 2 * k + 1);
  }
  // merge chain B into chain A with (d, idx) lexicographic order
  LEXINS(daA, dbA, dcA, iaA, ibA, icA, daB, iaB);
  LEXINS(daA, dbA, dcA, iaA, ibA, icA, dbB, ibB);
  LEXINS(daA, dbA, dcA, iaA, ibA, icA, dcB, icB);

  int q = b * N2 + n;
  int base = (q * NCH + ch) * 3;
  pd[base] = daA; pd[base + 1] = dbA; pd[base + 2] = dcA;
  pi[base] = (unsigned short)iaA;
  pi[base + 1] = (unsigned short)ibA;
  pi[base + 2] = (unsigned short)icA;
}

// ---------------------------------------------------------------------------
// k_merge: combine NCH chunk-partial top-3s (chunk order == index order and
// each partial is (d,idx)-sorted, so plain strict-< insertion reproduces
// stable top-k), then the exact reference weight arithmetic.
// ---------------------------------------------------------------------------
__global__ __launch_bounds__(256) void k_merge(
    const float* __restrict__ pd, const unsigned short* __restrict__ pi,
    float* __restrict__ wbuf, int* __restrict__ ibuf) {
  int q = blockIdx.x * 256 + threadIdx.x;    // 128 blocks
  float da = 3.0e38f, db = 3.0e38f, dc = 3.0e38f;
  int ia = 0, ib = 0, ic = 0;
#pragma unroll
  for (int ch = 0; ch < NCH; ++ch) {
    int base = (q * NCH + ch) * 3;
#pragma unroll
    for (int k = 0; k < 3; ++k) {
      float dd = pd[base + k];
      int jj = (int)pi[base + k];
      INS(da, db, dc, ia, ib, ic, dd, jj);
    }
  }
  float qa = fmaxf(da, 0.0f), qb = fmaxf(db, 0.0f), qc = fmaxf(dc, 0.0f);
  qa = fmaxf(__fmul_rn(qa, qa), 1e-10f);
  qb = fmaxf(__fmul_rn(qb, qb), 1e-10f);
  qc = fmaxf(__fmul_rn(qc, qc), 1e-10f);
  float va = __fdiv_rn(1.0f, qa);
  float vb = __fdiv_rn(1.0f, qb);
  float vc = __fdiv_rn(1.0f, qc);
  float s = __fadd_rn(__fadd_rn(va, vb), vc);
  wbuf[q]           = __fdiv_rn(va, s);
  wbuf[BQ + q]      = __fdiv_rn(vb, s);
  wbuf[2 * BQ + q]  = __fdiv_rn(vc, s);
  ibuf[q]          = ia;
  ibuf[BQ + q]     = ib;
  ibuf[2 * BQ + q] = ic;
}

// ---------------------------------------------------------------------------
// k_transpose: features1 [B,C1,N1] -> f1T [B,N1,C1] (contiguous gather rows).
// NOTE: f1T aliases pd/pi — must launch after k_merge.
// ---------------------------------------------------------------------------
__global__ __launch_bounds__(256) void k_transpose(
    const float* __restrict__ f1, float* __restrict__ f1T) {
  __shared__ float tile[64][65];
  const int bx = blockIdx.x;            // B * 4(ct) * 64(nt) = 512
  const int b = bx >> 8;
  const int rest = bx & 255;
  const int ct = rest >> 6;
  const int ntb = (rest & 63) << 6;
  const int t = threadIdx.x;
  const int ln = t & 63, g = t >> 6;

  const float* src = f1 + ((size_t)b * C1 + ct * 64) * N1 + ntb;
  for (int k = 0; k < 16; ++k) {
    int c = (k << 2) + g;
    tile[c][ln] = src[(size_t)c * N1 + ln];
  }
  __syncthreads();
  float* dst = f1T + ((size_t)b * N1 + ntb) * C1 + ct * 64;
  for (int k = 0; k < 16; ++k) {
    int nn = (k << 2) + g;
    dst[(size_t)nn * C1 + ln] = tile[ln][nn];
  }
}

// ---------------------------------------------------------------------------
// k_fused: gather+interp -> bf16 LDS [col][k] -> MFMA GEMM1 -> BN1+ReLU ->
// bf16 LDS h -> MFMA GEMM2 -> BN2+ReLU -> out (fp32).
// 256 threads = 4 waves; wave wv owns output rows [wv*64, wv*64+64), all 64
// cols of the block's n-tile: 4x4 tiles of mfma_f32_16x16x32_bf16.
// ---------------------------------------------------------------------------
__global__ __launch_bounds__(256) void k_fused(
    const float* __restrict__ f1T, const float* __restrict__ f2,
    const float* __restrict__ wbuf, const int* __restrict__ ibuf,
    const __bf16* __restrict__ W1b, const __bf16* __restrict__ W2b,
    const float* __restrict__ scsh, float* __restrict__ out) {
  __shared__ __bf16 sX[64 * KPAD];       // 49KB; x for GEMM1, then h for GEMM2
  const int t = threadIdx.x;
  const int bx = blockIdx.x;
  const int b = bx >> 8;
  const int n0 = (bx & 255) << 6;

  // ---- Phase A1: interp C1 channels (k = 0..255) ----
  {
    const int nn = t >> 2, qq = t & 3;   // 4 threads per column
    const int gi = b * N2 + n0 + nn;
    const float w0 = wbuf[gi], w1 = wbuf[BQ + gi], w2 = wbuf[2 * BQ + gi];
    const int i0 = ibuf[gi], i1 = ibuf[BQ + gi], i2 = ibuf[2 * BQ + gi];
    const float4* r0 = (const float4*)(f1T + ((size_t)b * N1 + i0) * C1);
    const float4* r1 = (const float4*)(f1T + ((size_t)b * N1 + i1) * C1);
    const float4* r2 = (const float4*)(f1T + ((size_t)b * N1 + i2) * C1);
#pragma unroll 4
    for (int m = 0; m < 16; ++m) {
      int idx4 = (qq << 4) + m;
      float4 a = r0[idx4], c4 = r1[idx4], d4 = r2[idx4];
      bf16x4 v;
      v[0] = (__bf16)fmaf(w0, a.x, fmaf(w1, c4.x, w2 * d4.x));
      v[1] = (__bf16)fmaf(w0, a.y, fmaf(w1, c4.y, w2 * d4.y));
      v[2] = (__bf16)fmaf(w0, a.z, fmaf(w1, c4.z, w2 * d4.z));
      v[3] = (__bf16)fmaf(w0, a.w, fmaf(w1, c4.w, w2 * d4.w));
      *(bf16x4*)&sX[nn * KPAD + (idx4 << 2)] = v;
    }
  }
  // ---- Phase A2: features2 channels (k = 256..383) ----
  {
    const int col = t & 63, g = t >> 6;
    const float* f2b = f2 + (size_t)b * C2 * N2 + n0 + col;
#pragma unroll 2
    for (int m = 0; m < 8; ++m) {
      int c4 = (g << 5) + (m << 2);
      bf16x4 v;
      v[0] = (__bf16)f2b[(size_t)(c4 + 0) * N2];
      v[1] = (__bf16)f2b[(size_t)(c4 + 1) * N2];
      v[2] = (__bf16)f2b[(size_t)(c4 + 2) * N2];
      v[3] = (__bf16)f2b[(size_t)(c4 + 3) * N2];
      *(bf16x4*)&sX[col * KPAD + 256 + c4] = v;
    }
  }
  __syncthreads();

  const int l  = t & 63;
  const int wv = __builtin_amdgcn_readfirstlane(t >> 6);
  const int ob = wv << 6;
  const int lm = l & 15, lg = l >> 4;

  f32x4 acc[4][4];
#pragma unroll
  for (int mt = 0; mt < 4; ++mt)
#pragma unroll
    for (int nt = 0; nt < 4; ++nt) acc[mt][nt] = (f32x4)0.0f;

  // ---- GEMM1: K = 384 (12 k-steps) ----
  for (int ks = 0; ks < 12; ++ks) {
    bf16x8 af[4], bfr[4];
#pragma unroll
    for (int mt = 0; mt < 4; ++mt)
      af[mt] = *(const bf16x8*)(W1b + (size_t)(ob + mt * 16 + lm) * K1 +
                                ks * 32 + lg * 8);
#pragma unroll
    for (int nt = 0; nt < 4; ++nt)
      bfr[nt] = *(const bf16x8*)&sX[(nt * 16 + lm) * KPAD + ks * 32 + lg * 8];
#pragma unroll
    for (int mt = 0; mt < 4; ++mt)
#pragma unroll
      for (int nt = 0; nt < 4; ++nt)
        acc[mt][nt] = __builtin_amdgcn_mfma_f32_16x16x32_bf16(
            af[mt], bfr[nt], acc[mt][nt], 0, 0, 0);
  }
  __syncthreads();

  // ---- BN1 + ReLU -> h (bf16) back into sX ----
#pragma unroll
  for (int mt = 0; mt < 4; ++mt) {
    int rb = ob + mt * 16 + lg * 4;     // h-channel base (GEMM1 output row)
    float4 sc4 = *(const float4*)(scsh + rb);
    float4 sh4 = *(const float4*)(scsh + HH + rb);
#pragma unroll
    for (int nt = 0; nt < 4; ++nt) {
      int colc = nt * 16 + lm;
      bf16x4 v;
      v[0] = (__bf16)fmaxf(fmaf(acc[mt][nt][0], sc4.x, sh4.x), 0.0f);
      v[1] = (__bf16)fmaxf(fmaf(acc[mt][nt][1], sc4.y, sh4.y), 0.0f);
      v[2] = (__bf16)fmaxf(fmaf(acc[mt][nt][2], sc4.z, sh4.z), 0.0f);
      v[3] = (__bf16)fmaxf(fmaf(acc[mt][nt][3], sc4.w, sh4.w), 0.0f);
      *(bf16x4*)&sX[colc * KPAD + rb] = v;
    }
  }
  __syncthreads();

  // ---- GEMM2: K = 256 (8 k-steps) ----
  f32x4 ac2[4][4];
#pragma unroll
  for (int mt = 0; mt < 4; ++mt)
#pragma unroll
    for (int nt = 0; nt < 4; ++nt) ac2[mt][nt] = (f32x4)0.0f;
  for (int ks = 0; ks < 8; ++ks) {
    bf16x8 af[4], bfr[4];
#pragma unroll
    for (int mt = 0; mt < 4; ++mt)
      af[mt] = *(const bf16x8*)(W2b + (size_t)(ob + mt * 16 + lm) * HH +
                                ks * 32 + lg * 8);
#pragma unroll
    for (int nt = 0; nt < 4; ++nt)
      bfr[nt] = *(const bf16x8*)&sX[(nt * 16 + lm) * KPAD + ks * 32 + lg * 8];
#pragma unroll
    for (int mt = 0; mt < 4; ++mt)
#pragma unroll
      for (int nt = 0; nt < 4; ++nt)
        ac2[mt][nt] = __builtin_amdgcn_mfma_f32_16x16x32_bf16(
            af[mt], bfr[nt], ac2[mt][nt], 0, 0, 0);
  }

  // ---- BN2 + ReLU -> out (fp32) ----
  float* outb = out + (size_t)b * HH * N2 + n0;
#pragma unroll
  for (int mt = 0; mt < 4; ++mt) {
    int rb = ob + mt * 16 + lg * 4;
    float4 sc4 = *(const float4*)(scsh + 2 * HH + rb);
    float4 sh4 = *(const float4*)(scsh + 3 * HH + rb);
#pragma unroll
    for (int nt = 0; nt < 4; ++nt) {
      int colc = nt * 16 + lm;
      outb[(size_t)(rb + 0) * N2 + colc] =
          fmaxf(fmaf(ac2[mt][nt][0], sc4.x, sh4.x), 0.0f);
      outb[(size_t)(rb + 1) * N2 + colc] =
          fmaxf(fmaf(ac2[mt][nt][1], sc4.y, sh4.y), 0.0f);
      outb[(size_t)(rb + 2) * N2 + colc] =
          fmaxf(fmaf(ac2[mt][nt][2], sc4.z, sh4.z), 0.0f);
      outb[(size_t)(rb + 3) * N2 + colc] =
          fmaxf(fmaf(ac2[mt][nt][3], sc4.w, sh4.w), 0.0f);
    }
  }
}

// ---------------------------------------------------------------------------
extern "C" void kernel_launch(void* const* d_in, const int* in_sizes, int n_in,
                              void* d_out, int out_size, void* d_ws, size_t ws_size,
                              hipStream_t stream) {
  const float* p1  = (const float*)d_in[0];
  const float* p2  = (const float*)d_in[1];
  const float* f1  = (const float*)d_in[2];
  const float* f2  = (const float*)d_in[3];
  const float* W1  = (const float*)d_in[4];
  const float* bb1 = (const float*)d_in[5];
  const float* g1  = (const float*)d_in[6];
  const float* be1 = (const float*)d_in[7];
  const float* mm1 = (const float*)d_in[8];
  const float* vv1 = (const float*)d_in[9];
  const float* W2  = (const float*)d_in[10];
  const float* bb2 = (const float*)d_in[11];
  const float* g2  = (const float*)d_in[12];
  const float* be2 = (const float*)d_in[13];
  const float* mm2 = (const float*)d_in[14];
  const float* vv2 = (const float*)d_in[15];
  float* out = (float*)d_out;

  // ws layout. pd/pi live only between k_nn and k_merge, then the same bytes
  // are reused for f1T (k_transpose launches after k_merge).
  char* ws = (char*)d_ws;
  float*          pd   = (float*)(ws);                 // 6,291,456 B
  unsigned short* pi   = (unsigned short*)(ws + 6291456); // 3,145,728 B
  float*          f1T  = (float*)(ws);                 // 8,388,608 B (alias)
  float*          wbuf = (float*)(ws + 9437184);       //   393,216 B
  int*            ibuf = (int*)  (ws + 9830400);       //   393,216 B
  float*          pts8 = (float*)(ws + 10223616);      //   131,072 B
  __bf16*         W1b  = (__bf16*)(ws + 10354688);     //   196,608 B
  __bf16*         W2b  = (__bf16*)(ws + 10551296);     //   131,072 B
  float*          scsh = (float*)(ws + 10682368);      //     4,096 B

  k_prep<<<384, 256, 0, stream>>>(p1, W1, W2,
                                  bb1, g1, be1, mm1, vv1,
                                  bb2, g2, be2, mm2, vv2,
                                  pts8, W1b, W2b, scsh);
  k_nn<<<2048, 256, 0, stream>>>(p2, (const float4*)pts8, pd, pi);
  k_merge<<<128, 256, 0, stream>>>(pd, pi, wbuf, ibuf);
  k_transpose<<<512, 256, 0, stream>>>(f1, f1T);   // after k_merge: reuses pd/pi
  k_fused<<<512, 256, 0, stream>>>(f1T, f2, wbuf, ibuf, W1b, W2b, scsh, out);
}